// Round 16
// baseline (70.746 us; speedup 1.0000x reference)
//
#include <hip/hip_runtime.h>

// DCNv2: DECOUPLED im2col + GEMM.
//  A0: bilinear params -> SPG table (global)
//  A : pure-streaming gather/bilinear -> Bm[pix][k] f16 (75 MB), no barriers
//  B : R15 GEMM skeleton, B-tile now LINEAR loads from Bm (no gathers in loop)
// ws: [0, 8388608)        xt  = x transposed to (n, hw, C) f16
//     [8388608, 9568256)  wt2 = weight tiled [f][q][r][kq] f16
//     [9568256, 14286848) SPG = 147456 x 32B bilinear params
//     [14286848, 89784320) Bm = im2col [16384 pix][2304 k] f16
//     [89784320, +2*8388608) parts[2] = k-half partials f16

typedef _Float16 f16x8 __attribute__((ext_vector_type(8)));
typedef _Float16 f16x4 __attribute__((ext_vector_type(4)));
typedef float f32x4 __attribute__((ext_vector_type(4)));

#define C_IN 256
#define CO   256
#define KK   9
#define HWSZ 4096
#define LDB  72
#define BUFB (64 * LDB)
#define PSTR (4 * CO * HWSZ)
#define KROW 4608               // Bm row bytes (2304 f16)

struct __align__(16) SP2 { uint4 off; f16x4 w; };   // 32 B

static __device__ __forceinline__ f16x8 splat8(_Float16 v) {
    f16x8 r = {v, v, v, v, v, v, v, v};
    return r;
}

// ---- transpose x: (N,C,64,64) f32 -> xt[n][p][c] f16 ----
__global__ void transpose_x_kernel(const float* __restrict__ x,
                                   _Float16* __restrict__ xt) {
    __shared__ float tile[64][65];
    const int n  = blockIdx.z;
    const int p0 = blockIdx.x * 64;
    const int c0 = blockIdx.y * 64;
    const int tx = threadIdx.x & 63;
    const int ty = threadIdx.x >> 6;
    for (int i = 0; i < 16; ++i) {
        int c = ty * 16 + i;
        tile[c][tx] = x[((size_t)(n * C_IN + c0 + c) << 12) + p0 + tx];
    }
    __syncthreads();
    for (int i = 0; i < 16; ++i) {
        int p = ty * 16 + i;
        xt[((size_t)((n << 12) + p0 + p) << 8) + c0 + tx] = (_Float16)tile[tx][p];
    }
}

// ---- weight: (Co,C,3,3) f32 -> wt2[((f*72+q)*16+r)*32+kq] f16 ----
__global__ void transpose_w_kernel(const float* __restrict__ w,
                                   _Float16* __restrict__ wt2) {
    const int o = blockIdx.x;
    const int c = threadIdx.x;
    const int f = o >> 4, r = o & 15, cc = c >> 5, kq = c & 31;
    for (int kk = 0; kk < KK; ++kk) {
        int q = cc * 9 + kk;
        wt2[((f * 72 + q) * 16 + r) * 32 + kq] =
            (_Float16)w[(o * C_IN + c) * KK + kk];
    }
}

// ---- A0: bilinear params for all (pix, tap) -> SPG ----
__global__ void params_kernel(const float* __restrict__ offset,
                              const float* __restrict__ mask,
                              SP2* __restrict__ SPG) {
    const int t = blockIdx.x * 256 + threadIdx.x;   // 0..147455
    const int pix = t / 9;
    const int k   = t - pix * 9;
    const int n   = pix >> 12;
    const int phw = pix & 4095;
    const int h = phw >> 6, w = phw & 63;
    float dy = offset[(size_t)(n * 18 + 2 * k)     * HWSZ + phw];
    float dx = offset[(size_t)(n * 18 + 2 * k + 1) * HWSZ + phw];
    float mv = mask  [(size_t)(n * 9 + k)          * HWSZ + phw];
    float py = dy + (float)(h - 1 + k / 3);
    float px = dx + (float)(w - 1 + k % 3);
    float y0f = floorf(py), x0f = floorf(px);
    int y0 = (int)y0f, x0 = (int)x0f;
    float wy1 = py - y0f, wx1 = px - x0f;
    float wy0 = 1.f - wy1, wx0 = 1.f - wx1;
    int y1 = y0 + 1, x1 = x0 + 1;
    float vy0 = (y0 >= 0 && y0 < 64) ? 1.f : 0.f;
    float vy1 = (y1 >= 0 && y1 < 64) ? 1.f : 0.f;
    float vx0 = (x0 >= 0 && x0 < 64) ? 1.f : 0.f;
    float vx1 = (x1 >= 0 && x1 < 64) ? 1.f : 0.f;
    int cy0 = min(max(y0, 0), 63), cy1 = min(max(y1, 0), 63);
    int cx0 = min(max(x0, 0), 63), cx1 = min(max(x1, 0), 63);
    SP2 e;
    e.off = make_uint4((unsigned)(cy0 * 64 + cx0) << 9,
                       (unsigned)(cy0 * 64 + cx1) << 9,
                       (unsigned)(cy1 * 64 + cx0) << 9,
                       (unsigned)(cy1 * 64 + cx1) << 9);
    f16x4 wv;
    wv.x = (_Float16)(wy0 * wx0 * mv * vy0 * vx0);
    wv.y = (_Float16)(wy0 * wx1 * mv * vy0 * vx1);
    wv.z = (_Float16)(wy1 * wx0 * mv * vy1 * vx0);
    wv.w = (_Float16)(wy1 * wx1 * mv * vy1 * vx1);
    e.w = wv;
    SPG[t] = e;
}

// ---- A: im2col materialize. Pure streaming: no barriers, no LDS. ----
// thread = (team = pix*9+tap, oct); 8 chunks of 32 chans each.
__global__ void im2col_kernel(const SP2* __restrict__ SPG,
                              const _Float16* __restrict__ xt,
                              _Float16* __restrict__ Bm) {
    const int g    = blockIdx.x * 256 + threadIdx.x;  // 0..589823
    const int team = g >> 2;
    const int oct  = g & 3;
    const int pix  = team / 9;
    const int tap  = team - pix * 9;
    const int n    = pix >> 12;
    const SP2 e = SPG[team];
    const char* xb = (const char*)xt + ((size_t)n << 21);
    char* bo = (char*)Bm + (size_t)pix * KROW + tap * 64 + oct * 16;
#pragma unroll
    for (int cc = 0; cc < 8; ++cc) {
        const unsigned c_ = (unsigned)(cc * 64 + oct * 16);
        f16x8 g0 = *(const f16x8*)(xb + (e.off.x + c_));
        f16x8 g1 = *(const f16x8*)(xb + (e.off.y + c_));
        f16x8 g2 = *(const f16x8*)(xb + (e.off.z + c_));
        f16x8 g3 = *(const f16x8*)(xb + (e.off.w + c_));
        f16x8 r = g0 * splat8(e.w.x) + g1 * splat8(e.w.y)
                + g2 * splat8(e.w.z) + g3 * splat8(e.w.w);
        *(f16x8*)(bo + cc * 576) = r;   // q = cc*9+tap -> byte q*64
    }
}

// ---- B: GEMM 256Co x 64pix x K-half; B-tile = linear loads from Bm ----
template <int NHALF>
__launch_bounds__(256, 3)
__global__ void dcn_gemm_kernel(const _Float16* __restrict__ Bm,
                                const _Float16* __restrict__ wt2,
                                const float* __restrict__ bias,
                                float* __restrict__ out,
                                _Float16* __restrict__ parts) {
    constexpr int NS = 36 / NHALF;      // K-steps of 64 (2 q's)
    __shared__ _Float16 sB[2][BUFB];

    const int tid = threadIdx.x;
    const int cpx = (256 * NHALF) >> 3;
    const int lin = blockIdx.x;
    const int id  = (lin & 7) * cpx + (lin >> 3);   // XCD-contiguous
    const int half = (NHALF == 2) ? (id >> 8) : 0;
    const int pt   = id & 255;
    const int p0   = pt * 64;
    const int n    = p0 >> 12;
    const int phw0 = p0 & 4095;
    const int cc0  = half * 4;

    const int lane = tid & 63;
    const int wid  = tid >> 6;   // M slab (64 Co each)
    const int l15  = lane & 15;
    const int lhi  = lane >> 4;

    const int pixl = tid >> 2;   // staging pixel 0..63
    const int oct  = tid & 3;

    const char* wtb = (const char*)wt2;
    const char* bmb = (const char*)Bm + (size_t)(p0) * KROW
                    + (unsigned)(cc0 * 576);

    const int vBe = l15 * LDB + lhi * 8;
    const int vWe = pixl * LDB + oct * 8;

    unsigned voffA[4];
    for (int fm = 0; fm < 4; ++fm) {
        int fglob = wid * 4 + fm;
        voffA[fm] = (unsigned)((fglob * 72 + cc0 * 9) * 1024 + l15 * 64 + lhi * 16);
    }

    f16x8 bb[2][2];   // B stage, slot = feeding-step & 1 (2-deep)
    f16x8 aa[2][8];   // A fragments, 1-deep ahead
    f32x4 acc[4][4];
    for (int i = 0; i < 4; ++i)
        for (int j = 0; j < 4; ++j)
            acc[i][j] = (f32x4){0.f, 0.f, 0.f, 0.f};

#define ISSUE_B(T, SLOT)                                                      \
    {                                                                         \
        const char* b_ = bmb + (size_t)pixl * KROW + (T) * 128 + oct * 16;    \
        bb[SLOT][0] = *(const f16x8*)(b_);                                    \
        bb[SLOT][1] = *(const f16x8*)(b_ + 64);                               \
    }

#define ISSUE_A(T, SLOT)                                                      \
    {                                                                         \
        for (int fm_ = 0; fm_ < 4; ++fm_) {                                   \
            unsigned vo_ = voffA[fm_] + (unsigned)((T) * 2048);               \
            aa[SLOT][fm_ * 2 + 0] = *(const f16x8*)(wtb + vo_);               \
            aa[SLOT][fm_ * 2 + 1] = *(const f16x8*)(wtb + vo_ + 1024);        \
        }                                                                     \
    }

#define BSTORE(SLOT, BUF)                                                     \
    {                                                                         \
        _Float16* bw_ = &sB[0][0] + (BUF) * BUFB + vWe;                       \
        *(f16x8*)(bw_)      = bb[SLOT][0];                                    \
        *(f16x8*)(bw_ + 32) = bb[SLOT][1];                                    \
    }

#define MFMA_STEP(SLOT, BUF)                                                  \
    {                                                                         \
        const _Float16* br_ = &sB[0][0] + (BUF) * BUFB + vBe;                 \
        for (int fn_ = 0; fn_ < 4; ++fn_) {                                   \
            f16x8 bE_ = *(const f16x8*)(br_ + fn_ * 16 * LDB);                \
            f16x8 bO_ = *(const f16x8*)(br_ + fn_ * 16 * LDB + 32);           \
            for (int fm_ = 0; fm_ < 4; ++fm_) {                               \
                acc[fm_][fn_] = __builtin_amdgcn_mfma_f32_16x16x32_f16(       \
                    aa[SLOT][fm_ * 2 + 0], bE_, acc[fm_][fn_], 0, 0, 0);      \
                acc[fm_][fn_] = __builtin_amdgcn_mfma_f32_16x16x32_f16(       \
                    aa[SLOT][fm_ * 2 + 1], bO_, acc[fm_][fn_], 0, 0, 0);      \
            }                                                                 \
        }                                                                     \
    }

#define BAR()                                                                 \
    {                                                                         \
        asm volatile("s_waitcnt lgkmcnt(0)" ::: "memory");                    \
        __builtin_amdgcn_s_barrier();                                         \
        asm volatile("" ::: "memory");                                        \
    }

    // prologue
    ISSUE_B(0, 0)
    ISSUE_B(1, 1)
    ISSUE_A(0, 0)
    BSTORE(0, 0)
    BAR()

#pragma unroll
    for (int s = 0; s < NS; ++s) {
        if (s + 1 < NS) ISSUE_A(s + 1, (s + 1) & 1)   // feeds MFMA(s+1)
        if (s + 2 < NS) ISSUE_B(s + 2, s & 1)         // feeds BSTORE(s+2)
        __builtin_amdgcn_sched_barrier(0);
        MFMA_STEP(s & 1, s & 1)                       // leaves 12 loads flying
        if (s + 1 < NS) {
            BSTORE((s + 1) & 1, (s + 1) & 1)          // leaves 10 flying
            BAR()
        }
    }

    // epilogue: C/D col=lane&15 (pix), row=(lane>>4)*4+r (o)
    if constexpr (NHALF == 2) {
        _Float16* pp = parts + (size_t)half * PSTR;
        for (int fm = 0; fm < 4; ++fm)
            for (int fn = 0; fn < 4; ++fn) {
                int pix = phw0 + fn * 16 + l15;
                for (int r = 0; r < 4; ++r) {
                    int o = wid * 64 + fm * 16 + lhi * 4 + r;
                    pp[((size_t)(n * CO + o) << 12) + pix] =
                        (_Float16)acc[fm][fn][r];
                }
            }
    } else {
        for (int fm = 0; fm < 4; ++fm)
            for (int fn = 0; fn < 4; ++fn) {
                int pix = phw0 + fn * 16 + l15;
                for (int r = 0; r < 4; ++r) {
                    int o = wid * 64 + fm * 16 + lhi * 4 + r;
                    out[((size_t)(n * CO + o) << 12) + pix] =
                        acc[fm][fn][r] + bias[o];
                }
            }
    }
#undef ISSUE_B
#undef ISSUE_A
#undef BSTORE
#undef MFMA_STEP
#undef BAR
}

// ---- reduce: out = parts[0] + parts[1] + bias ----
__global__ void reduce_kernel(float* __restrict__ out,
                              const _Float16* __restrict__ parts,
                              const float* __restrict__ bias, int n8) {
    int i = blockIdx.x * blockDim.x + threadIdx.x;
    if (i >= n8) return;
    f16x8 a = ((const f16x8*)parts)[i];
    f16x8 b = ((const f16x8*)(parts + (size_t)PSTR))[i];
    float bv = bias[((i * 8) >> 12) & 255];
    f32x4 r0, r1;
    for (int e = 0; e < 4; ++e)
        r0[e] = (float)a[e] + (float)b[e] + bv;
    for (int e = 0; e < 4; ++e)
        r1[e] = (float)a[e + 4] + (float)b[e + 4] + bv;
    ((f32x4*)out)[2 * i]     = r0;
    ((f32x4*)out)[2 * i + 1] = r1;
}

extern "C" void kernel_launch(void* const* d_in, const int* in_sizes, int n_in,
                              void* d_out, int out_size, void* d_ws, size_t ws_size,
                              hipStream_t stream) {
    const float* x      = (const float*)d_in[0];
    const float* offset = (const float*)d_in[1];
    const float* mask   = (const float*)d_in[2];
    const float* weight = (const float*)d_in[3];
    const float* bias   = (const float*)d_in[4];
    float* out = (float*)d_out;

    _Float16* xt  = (_Float16*)d_ws;
    _Float16* wt2 = (_Float16*)((char*)d_ws + 8388608);
    SP2*      SPG = (SP2*)((char*)d_ws + 9568256);
    _Float16* Bm  = (_Float16*)((char*)d_ws + 14286848);
    _Float16* parts = (_Float16*)((char*)d_ws + 89784320);
    const bool split = ws_size >= (size_t)89784320 + (size_t)2 * PSTR * 2;

    transpose_x_kernel<<<dim3(64, 4, 4), 256, 0, stream>>>(x, xt);
    transpose_w_kernel<<<CO, C_IN, 0, stream>>>(weight, wt2);
    params_kernel<<<dim3(576), 256, 0, stream>>>(offset, mask, SPG);
    im2col_kernel<<<dim3(2304), 256, 0, stream>>>(SPG, xt, Bm);
    if (split) {
        dcn_gemm_kernel<2><<<dim3(512), 256, 0, stream>>>(Bm, wt2, bias,
                                                          out, parts);
        reduce_kernel<<<dim3(PSTR / 8 / 256), 256, 0, stream>>>(out, parts, bias,
                                                                PSTR / 8);
    } else {
        dcn_gemm_kernel<1><<<dim3(256), 256, 0, stream>>>(Bm, wt2, bias,
                                                          out, parts);
    }
}